// Round 5
// baseline (1004.446 us; speedup 1.0000x reference)
//
#include <hip/hip_runtime.h>
#include <hip/hip_bf16.h>

// B=2, N=1024, D=512, H=8, DH=64, HD=512, FF=2048, DEPTH=4.
// Dual-dtype IO (bf16 or fp32, runtime-detected from ln1_g word0).
// bf16 MFMA 16x16x32, fp32 accum, fp32 residual chain.
// LN fused into qkv/ff1 GEMM A-staging (row stats prologue).
// Scores: BD scatter-stored (rel_shift, injective, diag = zero set) into Scb;
// fused kernel: AC mfma (8 h-planes in regs) + Scb add + softmax-over-h -> attn.

using bf16 = __hip_bfloat16;
typedef __attribute__((ext_vector_type(8))) short short8;
typedef __attribute__((ext_vector_type(4))) float float4v;

__device__ __forceinline__ float ldsel(const void* p, long long i, bool isbf) {
    return isbf ? __bfloat162float(((const bf16*)p)[i]) : ((const float*)p)[i];
}
__device__ __forceinline__ void stsel(void* p, long long i, bool isbf, float v) {
    if (isbf) ((bf16*)p)[i] = __float2bfloat16(v);
    else      ((float*)p)[i] = v;
}

__global__ void detect_kernel(const unsigned int* __restrict__ g, int* __restrict__ flag) {
    if (threadIdx.x == 0) flag[0] = ((g[0] & 0xFFFFu) != 0u) ? 1 : 0;
}

// y=0: cast x_in -> xbuf (fp32); y=1..3: r_{t,c,p} -> rcat bf16 [m][s*512+k]
__global__ __launch_bounds__(256) void cast_rcat(
    const void* __restrict__ x_in, const void* __restrict__ r0,
    const void* __restrict__ r1, const void* __restrict__ r2,
    float* __restrict__ xbuf, bf16* __restrict__ rcat, const int* __restrict__ flagp) {
    bool bf = flagp[0] != 0;
    int y = blockIdx.y;
    int i = blockIdx.x * 256 + threadIdx.x;
    if (y == 0) {
        xbuf[i] = ldsel(x_in, i, bf);
    } else {
        const void* src = (y == 1) ? r0 : ((y == 2) ? r1 : r2);
        int m = i >> 9, k = i & 511;
        rcat[(size_t)m * 1536 + (y - 1) * 512 + k] = __float2bfloat16(ldsel(src, i, bf));
    }
}

__global__ __launch_bounds__(256) void cast_out(const float* __restrict__ in, void* __restrict__ out,
                                                int n, const int* __restrict__ flagp) {
    bool bf = flagp[0] != 0;
    int i = blockIdx.x * 256 + threadIdx.x;
    if (i < n) stsel(out, i, bf, in[i]);
}

// ---- all weight transposes (all 4 layers) in ONE dispatch, vectorized ----
struct TJobs {
    int src[28]; int srcoff[28]; int ldi[28];
    int dstoff[28]; int ldo[28]; int tx[28]; int ty[28];
};
__global__ __launch_bounds__(256) void prep_weights(
    const void* __restrict__ s0, const void* __restrict__ s1, const void* __restrict__ s2,
    const void* __restrict__ s3, const void* __restrict__ s4, const void* __restrict__ s5,
    const void* __restrict__ s6, TJobs jobs, bf16* __restrict__ arena,
    const int* __restrict__ flagp) {
    bool bf = flagp[0] != 0;
    int z = blockIdx.z;
    if ((int)blockIdx.x >= jobs.tx[z] || (int)blockIdx.y >= jobs.ty[z]) return;
    int sid = jobs.src[z];
    const void* in = (sid == 0) ? s0 : (sid == 1) ? s1 : (sid == 2) ? s2 :
                     (sid == 3) ? s3 : (sid == 4) ? s4 : (sid == 5) ? s5 : s6;
    long long ioff = jobs.srcoff[z];
    int ldi = jobs.ldi[z], ldo = jobs.ldo[z];
    bf16* out = arena + jobs.dstoff[z];
    // 64x64 tile: out[n][k] = in[k][n]. XOR-swizzled LDS: logical (k,n) stored at
    // t[k][ (n&7) + 8*((n>>3) ^ (k&7)) ].
    __shared__ bf16 t[64][64];
    int n0 = blockIdx.x * 64, k0 = blockIdx.y * 64;
    int tid = threadIdx.x;
    int kr = tid >> 3, nc8 = (tid & 7) * 8;   // load: 32 k-rows/pass, 8 n each
    #pragma unroll
    for (int p = 0; p < 2; ++p) {
        int k = kr + p * 32;
        long long src = ioff + (long long)(k0 + k) * ldi + n0 + nc8;
        union { bf16 h[8]; uint4 u; } w;
        if (bf) {
            w.u = *(const uint4*)((const bf16*)in + src);
        } else {
            float4 f0 = *(const float4*)((const float*)in + src);
            float4 f1 = *(const float4*)((const float*)in + src + 4);
            w.h[0] = __float2bfloat16(f0.x); w.h[1] = __float2bfloat16(f0.y);
            w.h[2] = __float2bfloat16(f0.z); w.h[3] = __float2bfloat16(f0.w);
            w.h[4] = __float2bfloat16(f1.x); w.h[5] = __float2bfloat16(f1.y);
            w.h[6] = __float2bfloat16(f1.z); w.h[7] = __float2bfloat16(f1.w);
        }
        *(uint4*)&t[k][nc8 ^ (8 * (k & 7))] = w.u;
    }
    __syncthreads();
    int nr = tid >> 3, kc8 = (tid & 7) * 8;   // store: 32 n-rows/pass, 8 k each (coalesced 128B)
    #pragma unroll
    for (int p = 0; p < 2; ++p) {
        int n = nr + p * 32;
        union { bf16 h[8]; uint4 u; } w;
        #pragma unroll
        for (int u = 0; u < 8; ++u)
            w.h[u] = t[kc8 + u][(n & 7) + 8 * ((n >> 3) ^ u)];
        *(uint4*)&out[(size_t)(n0 + n) * ldo + k0 + kc8] = w.u;
    }
}

// ---- MFMA GEMM: C[m,n] = sum_k A[m,k]*B[n,k] (NT). TMx64 tile, BK=32. ----
// TM=128: 4 waves 2x2, wave 64x32 (4x2 frags). TM=64: wave 32x32 (2x2 frags).
// LNA: A = fp32 xbuf (ld 512); per-row LN stats computed in prologue; gamma/beta in LDS.
// EPI: 1 qkv (n<512:+bias_pf; n<1024: plain; else vT scatter); 2 fp32 +bias+resid;
//      3 bf16 gelu(+bias); 4 rel-shift scatter-store v/3; 5 bf16 plain store.
template<int TM, int EPI, bool LNA>
__global__ __launch_bounds__(256) void mgemm(
    const void* __restrict__ Av, int lda, long long sAb, long long sAh,
    const bf16* __restrict__ B, int ldb, long long sBb, long long sBh,
    void* __restrict__ Cv, int ldc, long long sCb, long long sCh,
    int K,
    const void* __restrict__ bias, long long biasoff,
    const void* __restrict__ lng, long long lngoff,
    const void* __restrict__ lnbp, long long lnboff,
    float* __restrict__ resid, bf16* __restrict__ aux,
    const int* __restrict__ flagp) {
    const bool flg = flagp[0] != 0;
    const int tid = threadIdx.x;
    const int lane = tid & 63, wave = tid >> 6;
    const int m0 = blockIdx.y * TM, n0 = blockIdx.x * 64;
    const int zb = (int)(blockIdx.z >> 3), zh = (int)(blockIdx.z & 7);
    const bf16* A = (const bf16*)Av;
    const float* Ax = (const float*)Av;
    if (!LNA) A += (size_t)zb * sAb + (size_t)zh * sAh;
    B += (size_t)zb * sBb + (size_t)zh * sBh;

    __shared__ bf16 As[TM][40];
    __shared__ bf16 Bs[64][40];
    __shared__ float rowm[LNA ? TM : 1], rowr[LNA ? TM : 1];
    __shared__ float gls[LNA ? 512 : 1], bls[LNA ? 512 : 1];

    if constexpr (LNA) {
        static_assert(TM == 128, "LNA path assumes TM=128");
        for (int u = tid; u < 512; u += 256) {
            gls[u] = ldsel(lng, lngoff + u, flg);
            bls[u] = ldsel(lnbp, lnboff + u, flg);
        }
        int sr = tid >> 1, sh = tid & 1;
        const float* xr = Ax + (size_t)(m0 + sr) * lda + sh * 256;
        float s = 0.f, q = 0.f;
        #pragma unroll 8
        for (int u = 0; u < 256; u += 4) {
            float4 v = *(const float4*)(xr + u);
            s += v.x + v.y + v.z + v.w;
            q += v.x * v.x + v.y * v.y + v.z * v.z + v.w * v.w;
        }
        s += __shfl_xor(s, 1); q += __shfl_xor(q, 1);
        if (sh == 0) {
            float m = s * (1.f / 512.f);
            float var = q * (1.f / 512.f) - m * m;
            rowm[sr] = m; rowr[sr] = rsqrtf(var + 1e-5f);
        }
        __syncthreads();
    }

    const int ar = tid >> 2, ak = (tid & 3) * 8;
    const bf16* Bp = B + (size_t)(n0 + ar) * ldb + ak;

    constexpr int NI = TM / 32;
    float4v acc[NI][2] = {};
    const int wm = (wave >> 1) * (TM / 2), wn = (wave & 1) * 32;
    const int fr = lane & 15, fq = lane >> 4;

    // LNA-path A pointers / stats
    const float* p0 = nullptr; const float* p1 = nullptr;
    float mA = 0.f, rA = 1.f, mB = 0.f, rB = 1.f;
    if constexpr (LNA) {
        p0 = Ax + (size_t)(m0 + ar) * lda + ak;
        p1 = p0 + (size_t)64 * lda;
        mA = rowm[ar]; rA = rowr[ar];
        mB = rowm[ar + 64]; rB = rowr[ar + 64];
    }
    // prefetch (non-LNA)
    uint4 pa0 = {}, pa1 = {}, pb0 = {};
    const bf16* Ap0 = nullptr; const bf16* Ap1 = nullptr;
    if constexpr (!LNA) {
        Ap0 = A + (size_t)(m0 + ar) * lda + ak;
        pa0 = *(const uint4*)Ap0;
        if constexpr (TM == 128) { Ap1 = Ap0 + (size_t)64 * lda; pa1 = *(const uint4*)Ap1; }
        pb0 = *(const uint4*)Bp;
    }

    for (int k0 = 0; k0 < K; k0 += 32) {
        __syncthreads();
        if constexpr (LNA) {
            float4 f0 = *(const float4*)(p0 + k0);
            float4 f1 = *(const float4*)(p0 + k0 + 4);
            float4 g0 = *(const float4*)(p1 + k0);
            float4 g1 = *(const float4*)(p1 + k0 + 4);
            union { bf16 h[8]; uint4 u; } w0, w1;
            float fa[8] = {f0.x, f0.y, f0.z, f0.w, f1.x, f1.y, f1.z, f1.w};
            float fb[8] = {g0.x, g0.y, g0.z, g0.w, g1.x, g1.y, g1.z, g1.w};
            #pragma unroll
            for (int u = 0; u < 8; ++u) {
                int k = k0 + ak + u;
                w0.h[u] = __float2bfloat16((fa[u] - mA) * rA * gls[k] + bls[k]);
                w1.h[u] = __float2bfloat16((fb[u] - mB) * rB * gls[k] + bls[k]);
            }
            *(uint4*)&As[ar][ak] = w0.u;
            *(uint4*)&As[ar + 64][ak] = w1.u;
            *(uint4*)&Bs[ar][ak] = *(const uint4*)(Bp + k0);
        } else {
            *(uint4*)&As[ar][ak] = pa0;
            if constexpr (TM == 128) *(uint4*)&As[ar + 64][ak] = pa1;
            *(uint4*)&Bs[ar][ak] = pb0;
            if (k0 + 32 < K) {
                pa0 = *(const uint4*)(Ap0 + k0 + 32);
                if constexpr (TM == 128) pa1 = *(const uint4*)(Ap1 + k0 + 32);
                pb0 = *(const uint4*)(Bp + k0 + 32);
            }
        }
        __syncthreads();
        union { uint4 u; short8 s; } ua[NI], ub[2];
        #pragma unroll
        for (int i = 0; i < NI; ++i) ua[i].u = *(const uint4*)&As[wm + i * 16 + fr][fq * 8];
        #pragma unroll
        for (int j = 0; j < 2; ++j) ub[j].u = *(const uint4*)&Bs[wn + j * 16 + fr][fq * 8];
        #pragma unroll
        for (int i = 0; i < NI; ++i)
            #pragma unroll
            for (int j = 0; j < 2; ++j)
                acc[i][j] = __builtin_amdgcn_mfma_f32_16x16x32_bf16(ua[i].s, ub[j].s, acc[i][j], 0, 0, 0);
    }

    const long long coff = (long long)zb * sCb + (long long)zh * sCh;
    #pragma unroll
    for (int i = 0; i < NI; ++i) {
        #pragma unroll
        for (int j = 0; j < 2; ++j) {
            #pragma unroll
            for (int r = 0; r < 4; ++r) {
                int m = m0 + wm + i * 16 + fq * 4 + r;
                int n = n0 + wn + j * 16 + fr;
                float v = acc[i][j][r];
                if (EPI == 1) {
                    bf16* C = (bf16*)Cv;
                    if (n < 512) {
                        C[(size_t)m * ldc + n] = __float2bfloat16(v + ldsel(bias, biasoff + n, flg));
                    } else if (n < 1024) {
                        C[(size_t)m * ldc + n] = __float2bfloat16(v);
                    } else {
                        int h = (n >> 6) & 7, d = n & 63, ii = m & 1023, bb = m >> 10;
                        aux[(size_t)(bb * 8 + h) * 65536 + (size_t)d * 1024 + ii] = __float2bfloat16(v);
                    }
                } else if (EPI == 2) {
                    float* C = (float*)Cv;
                    C[(size_t)m * ldc + n] = v + ldsel(bias, biasoff + n, flg) + resid[(size_t)m * ldc + n];
                } else if (EPI == 3) {
                    bf16* C = (bf16*)Cv;
                    float t = v + ldsel(bias, biasoff + n, flg);
                    C[(size_t)m * ldc + n] = __float2bfloat16(0.5f * t * (1.f + erff(t * 0.70710678118f)));
                } else if (EPI == 4) {
                    bf16* C = (bf16*)Cv + coff;
                    int t = m * 1025 + n + 1;
                    int ii = (t >> 10) - 1;
                    if (ii >= 0) C[(size_t)ii * 1024 + (t & 1023)] = __float2bfloat16(v * (1.f / 3.f));
                } else if (EPI == 5) {
                    bf16* C = (bf16*)Cv + coff;
                    C[(size_t)m * ldc + n] = __float2bfloat16(v);
                }
            }
        }
    }
}

// ---- fused AC + BD + softmax-over-h: block = 64x64 (i,j) tile, loops h=0..7 ----
__global__ __launch_bounds__(256) void scores_kernel(
    const bf16* __restrict__ qkvb, const bf16* __restrict__ Scb,
    bf16* __restrict__ attn, void* __restrict__ oattn, const int* __restrict__ flagp) {
    const bool bf = flagp[0] != 0;
    const int tid = threadIdx.x;
    const int lane = tid & 63, wave = tid >> 6;
    const int j0 = blockIdx.x * 64, i0 = blockIdx.y * 64, b = blockIdx.z;

    __shared__ bf16 Qs[64][72];
    __shared__ bf16 Ks[64][72];

    const int r0 = tid >> 3, c0 = (tid & 7) * 8;
    const bf16* Qp = qkvb + (size_t)(b * 1024 + i0 + r0) * 1536 + c0;
    const bf16* Kp = qkvb + (size_t)(b * 1024 + j0 + r0) * 1536 + 512 + c0;

    const int wm = (wave >> 1) * 32, wn = (wave & 1) * 32;
    const int fr = lane & 15, fq = lane >> 4;

    float4v acc[8][2][2] = {};

    for (int h = 0; h < 8; ++h) {
        __syncthreads();
        *(uint4*)&Qs[r0][c0]      = *(const uint4*)(Qp + h * 64);
        *(uint4*)&Qs[r0 + 32][c0] = *(const uint4*)(Qp + (size_t)32 * 1536 + h * 64);
        *(uint4*)&Ks[r0][c0]      = *(const uint4*)(Kp + h * 64);
        *(uint4*)&Ks[r0 + 32][c0] = *(const uint4*)(Kp + (size_t)32 * 1536 + h * 64);
        __syncthreads();
        #pragma unroll
        for (int ks = 0; ks < 2; ++ks) {
            union { uint4 u; short8 s; } ua[2], ub[2];
            #pragma unroll
            for (int i = 0; i < 2; ++i) ua[i].u = *(const uint4*)&Qs[wm + i * 16 + fr][fq * 8 + ks * 32];
            #pragma unroll
            for (int j = 0; j < 2; ++j) ub[j].u = *(const uint4*)&Ks[wn + j * 16 + fr][fq * 8 + ks * 32];
            #pragma unroll
            for (int i = 0; i < 2; ++i)
                #pragma unroll
                for (int j = 0; j < 2; ++j)
                    acc[h][i][j] = __builtin_amdgcn_mfma_f32_16x16x32_bf16(ua[i].s, ub[j].s, acc[h][i][j], 0, 0, 0);
        }
    }

    const size_t pb = (size_t)b * 8388608;
    #pragma unroll
    for (int i = 0; i < 2; ++i) {
        #pragma unroll
        for (int j = 0; j < 2; ++j) {
            #pragma unroll
            for (int r = 0; r < 4; ++r) {
                int gi = i0 + wm + i * 16 + fq * 4 + r;
                int gj = j0 + wn + j * 16 + fr;
                size_t idx = pb + (size_t)gi * 1024 + gj;
                float d[8];
                float mx = -3.4e38f;
                #pragma unroll
                for (int h = 0; h < 8; ++h) {
                    float bd = (gj == gi + 1) ? 0.f
                               : __bfloat162float(Scb[idx + (size_t)h * 1048576]);
                    float v = (acc[h][i][j][r] + bd) * 0.125f;
                    d[h] = v; mx = fmaxf(mx, v);
                }
                float s = 0.f;
                #pragma unroll
                for (int h = 0; h < 8; ++h) { d[h] = __expf(d[h] - mx); s += d[h]; }
                float inv = 1.f / s;
                #pragma unroll
                for (int h = 0; h < 8; ++h) {
                    float a = d[h] * inv;
                    attn[idx + (size_t)h * 1048576] = __float2bfloat16(a);
                    if (oattn) stsel(oattn, 1048576 + (long long)(idx + (size_t)h * 1048576), bf, a);
                }
            }
        }
    }
}

extern "C" void kernel_launch(void* const* d_in, const int* in_sizes, int n_in,
                              void* d_out, int out_size, void* d_ws, size_t ws_size,
                              hipStream_t stream) {
    (void)in_sizes; (void)n_in; (void)out_size; (void)ws_size;
    const void* x_in    = d_in[0];
    const void* r_t     = d_in[1];
    const void* r_c     = d_in[2];
    const void* r_p     = d_in[3];
    const void* bias_pf = d_in[4];
    const void* ln1_g   = d_in[5];
    const void* ln1_b   = d_in[6];
    const void* w_qkv   = d_in[7];
    const void* w_outw  = d_in[8];
    const void* b_out   = d_in[9];
    const void* w_kt    = d_in[10];
    const void* w_kc    = d_in[11];
    const void* w_kp    = d_in[12];
    const void* ln2_g   = d_in[13];
    const void* ln2_b   = d_in[14];
    const void* w_ff1   = d_in[15];
    const void* b_ff1   = d_in[16];
    const void* w_ff2   = d_in[17];
    const void* b_ff2   = d_in[18];

    float* xbuf  = (float*)d_ws;                 // 1M fp32
    bf16* base16 = (bf16*)(xbuf + 1048576);
    bf16* Scb   = base16;                        // 16M (h1 aliases first 4M)
    bf16* h1    = base16;
    bf16* attn  = base16 + 16777216;             // 16M
    bf16* xnb   = attn + 16777216;               // 1M (attention out)
    bf16* qkvb  = xnb + 1048576;                 // 3M
    bf16* vT    = qkvb + 3145728;                // 1M
    bf16* wsum  = vT + 1048576;                  // 1M
    bf16* rcat  = wsum + 1048576;                // 3M
    bf16* arena = rcat + 3145728;                // 15.75M (4 layers' transposed W)
    int*  flagp = (int*)(arena + 15728640);

    const int LW = 3932160;
    const int QKV_O = 0, WCAT_O = 786432, OUT_O = 1572864, FF1_O = 1835008, FF2_O = 2883584;

    dim3 blk(256);

    detect_kernel<<<1, 64, 0, stream>>>((const unsigned int*)ln1_g, flagp);
    cast_rcat<<<dim3(4096, 4), blk, 0, stream>>>(x_in, r_t, r_c, r_p, xbuf, rcat, flagp);

    TJobs jobs;
    int z = 0;
    for (int l = 0; l < 4; ++l) {
        int L = l * LW;
        jobs.src[z]=0; jobs.srcoff[z]=l*786432;  jobs.ldi[z]=1536; jobs.dstoff[z]=L+QKV_O;      jobs.ldo[z]=512;  jobs.tx[z]=24; jobs.ty[z]=8;  ++z;
        jobs.src[z]=1; jobs.srcoff[z]=l*262144;  jobs.ldi[z]=512;  jobs.dstoff[z]=L+WCAT_O;     jobs.ldo[z]=1536; jobs.tx[z]=8;  jobs.ty[z]=8;  ++z;
        jobs.src[z]=2; jobs.srcoff[z]=l*262144;  jobs.ldi[z]=512;  jobs.dstoff[z]=L+WCAT_O+512; jobs.ldo[z]=1536; jobs.tx[z]=8;  jobs.ty[z]=8;  ++z;
        jobs.src[z]=3; jobs.srcoff[z]=l*262144;  jobs.ldi[z]=512;  jobs.dstoff[z]=L+WCAT_O+1024;jobs.ldo[z]=1536; jobs.tx[z]=8;  jobs.ty[z]=8;  ++z;
        jobs.src[z]=4; jobs.srcoff[z]=l*262144;  jobs.ldi[z]=512;  jobs.dstoff[z]=L+OUT_O;      jobs.ldo[z]=512;  jobs.tx[z]=8;  jobs.ty[z]=8;  ++z;
        jobs.src[z]=5; jobs.srcoff[z]=l*1048576; jobs.ldi[z]=2048; jobs.dstoff[z]=L+FF1_O;      jobs.ldo[z]=512;  jobs.tx[z]=32; jobs.ty[z]=8;  ++z;
        jobs.src[z]=6; jobs.srcoff[z]=l*1048576; jobs.ldi[z]=512;  jobs.dstoff[z]=L+FF2_O;      jobs.ldo[z]=2048; jobs.tx[z]=8;  jobs.ty[z]=32; ++z;
    }
    prep_weights<<<dim3(32, 32, 28), blk, 0, stream>>>(
        w_qkv, w_kt, w_kc, w_kp, w_outw, w_ff1, w_ff2, jobs, arena, flagp);

    for (int l = 0; l < 4; ++l) {
        const bf16* qkvT  = arena + l * LW + QKV_O;
        const bf16* wcatT = arena + l * LW + WCAT_O;
        const bf16* outT  = arena + l * LW + OUT_O;
        const bf16* ff1T  = arena + l * LW + FF1_O;
        const bf16* ff2T  = arena + l * LW + FF2_O;

        // qkv = LN1(x) @ qkvT^T (LN fused); q += bias_pf; v -> vT
        mgemm<128, 1, true><<<dim3(24, 16, 1), blk, 0, stream>>>(
            xbuf, 512, 0, 0, qkvT, 512, 0, 0,
            qkvb, 1536, 0, 0, 512, bias_pf, 0,
            ln1_g, (long long)l * 512, ln1_b, (long long)l * 512, nullptr, vT, flagp);
        // wsum = rcat @ wcatT^T
        mgemm<64, 5, false><<<dim3(8, 32, 1), blk, 0, stream>>>(
            rcat, 1536, 0, 0, wcatT, 1536, 0, 0,
            wsum, 512, 0, 0, 1536, nullptr, 0,
            nullptr, 0, nullptr, 0, nullptr, nullptr, flagp);
        // Scb = rel_shift(q . wsum)/3 (scatter-store)
        mgemm<128, 4, false><<<dim3(16, 8, 16), blk, 0, stream>>>(
            qkvb, 1536, 1572864, 64, wsum, 512, 524288, 64,
            Scb, 1024, 8388608, 1048576, 64, nullptr, 0,
            nullptr, 0, nullptr, 0, nullptr, nullptr, flagp);
        // fused AC + BD + softmax -> attn (+ d_out attn region on l=3)
        scores_kernel<<<dim3(16, 16, 2), blk, 0, stream>>>(
            qkvb, Scb, attn, (l == 3) ? d_out : nullptr, flagp);
        // out = attn @ vT^T -> xnb
        mgemm<64, 5, false><<<dim3(1, 16, 16), blk, 0, stream>>>(
            attn, 1024, 8388608, 1048576, vT, 1024, 524288, 65536,
            xnb, 512, 524288, 64, 1024, nullptr, 0,
            nullptr, 0, nullptr, 0, nullptr, nullptr, flagp);
        // x = out @ outT^T + b_out + x (fp32)
        mgemm<64, 2, false><<<dim3(8, 32, 1), blk, 0, stream>>>(
            xnb, 512, 0, 0, outT, 512, 0, 0,
            xbuf, 512, 0, 0, 512, b_out, (long long)l * 512,
            nullptr, 0, nullptr, 0, xbuf, nullptr, flagp);
        // h1 = gelu(LN2(x) @ ff1T^T + b_ff1) (LN fused)
        mgemm<128, 3, true><<<dim3(32, 16, 1), blk, 0, stream>>>(
            xbuf, 512, 0, 0, ff1T, 512, 0, 0,
            h1, 2048, 0, 0, 512, b_ff1, (long long)l * 2048,
            ln2_g, (long long)l * 512, ln2_b, (long long)l * 512, nullptr, nullptr, flagp);
        // x = h1 @ ff2T^T + b_ff2 + x (fp32)
        mgemm<64, 2, false><<<dim3(8, 32, 1), blk, 0, stream>>>(
            h1, 2048, 0, 0, ff2T, 2048, 0, 0,
            xbuf, 512, 0, 0, 2048, b_ff2, (long long)l * 512,
            nullptr, 0, nullptr, 0, xbuf, nullptr, flagp);
    }

    cast_out<<<4096, blk, 0, stream>>>(xbuf, d_out, 1048576, flagp);
}